// Round 12
// baseline (322.568 us; speedup 1.0000x reference)
//
#include <hip/hip_runtime.h>
#include <math.h>

#define NPTS 40000
#define KNBR 16
#define BN_EPS 1e-5f

typedef __attribute__((ext_vector_type(8))) short v8s;
typedef __attribute__((ext_vector_type(4))) float f32x4;

__device__ __forceinline__ unsigned short f2bf(float f) {
    union { float f; unsigned int u; } c; c.f = f;
    unsigned int u = c.u + 0x7fffu + ((c.u >> 16) & 1u);   // RNE
    return (unsigned short)(u >> 16);
}
__device__ __forceinline__ float bflo(unsigned int u) {
    union { unsigned int u; float f; } c; c.u = u << 16; return c.f;
}
__device__ __forceinline__ float bfhi(unsigned int u) {
    union { unsigned int u; float f; } c; c.u = u & 0xffff0000u; return c.f;
}
__device__ __forceinline__ float bf2f(unsigned short u) {
    union { unsigned int u; float f; } c; c.u = ((unsigned int)u) << 16; return c.f;
}

// ---------------------------------------------------------------------------
// K1: per-point normals + B1[j][64] = [pos_j, normal_j] @ W1[0:6] + b1 (bf16)
// ---------------------------------------------------------------------------
__global__ __launch_bounds__(256, 4)
void k1_b1(const float* __restrict__ pos, const int* __restrict__ nbr,
           const float* __restrict__ W1, const float* __restrict__ b1,
           unsigned short* __restrict__ B1) {
    int p = blockIdx.x * 4 + (threadIdx.x >> 6);
    int k = threadIdx.x & 63;
    float px = pos[p * 3 + 0], py = pos[p * 3 + 1], pz = pos[p * 3 + 2];
    int n0 = nbr[p * KNBR + 0], n1 = nbr[p * KNBR + 1];
    float ax = pos[n0 * 3 + 0] - px, ay = pos[n0 * 3 + 1] - py, az = pos[n0 * 3 + 2] - pz;
    float bx = pos[n1 * 3 + 0] - px, by = pos[n1 * 3 + 1] - py, bz = pos[n1 * 3 + 2] - pz;
    float cx = ay * bz - az * by;
    float cy = az * bx - ax * bz;
    float cz = ax * by - ay * bx;
    float nrm = sqrtf(cx * cx + cy * cy + cz * cz);
    float inv = 1.0f / fmaxf(nrm, 1e-12f);
    float ux, uy, uz;
    if (nrm > 0.0f) { ux = cx * inv; uy = cy * inv; uz = cz * inv; }
    else            { ux = 0.0f;     uy = 0.0f;     uz = 1.0f;     }
    float acc = b1[k];
    acc = fmaf(px, W1[0 * 64 + k], acc);
    acc = fmaf(py, W1[1 * 64 + k], acc);
    acc = fmaf(pz, W1[2 * 64 + k], acc);
    acc = fmaf(ux, W1[3 * 64 + k], acc);
    acc = fmaf(uy, W1[4 * 64 + k], acc);
    acc = fmaf(uz, W1[5 * 64 + k], acc);
    B1[p * 64 + k] = f2bf(acc);
}

// ---------------------------------------------------------------------------
// K2: conv1 + k3 folded. Self rows amortized (wave-split prologue, bf16 Ssb).
// Per point: 16 neighbor rows, 4 MFMA/wave. h -> LDS H; epilogue A2 = H@W3+b3.
// ---------------------------------------------------------------------------
#define PTS2 32
__global__ __launch_bounds__(256, 2)
void k2_conv1_mfma(const float* __restrict__ pos, const int* __restrict__ nbr,
                   const unsigned short* __restrict__ B1, const float* __restrict__ W1,
                   const float* __restrict__ g1, const float* __restrict__ bt1,
                   const float* __restrict__ m1, const float* __restrict__ v1,
                   const float* __restrict__ W2, const float* __restrict__ b2,
                   const float* __restrict__ W3, const float* __restrict__ b3,
                   unsigned short* __restrict__ A2) {
    __shared__ __align__(16) unsigned char Tl[2][16 * 128];  // 4KB
    __shared__ __align__(16) unsigned char Hl[32 * 256];     // 8KB
    __shared__ unsigned short Ssb[32 * 128];                 // 8KB (bf16 self scores)

    const int tid  = threadIdx.x;
    const int wv   = tid >> 6;
    const int lane = tid & 63;
    const int lgrp = lane >> 4;
    const int lmod = lane & 15;

    v8s Bf2[2][2];
    float b2c[2];
#pragma unroll
    for (int nt = 0; nt < 2; ++nt) {
        const int col = wv * 32 + nt * 16 + lmod;
        b2c[nt] = b2[col];
#pragma unroll
        for (int kt = 0; kt < 2; ++kt)
#pragma unroll
            for (int j = 0; j < 8; ++j)
                Bf2[nt][kt][j] = (short)f2bf(W2[(kt * 32 + lgrp * 8 + j) * 128 + col]);
    }
    const int ch0 = (lane & 31) * 2;
    const int rsub = lane >> 5;
    const float w6a = W1[6 * 64 + ch0],     w7a = W1[7 * 64 + ch0],     w8a = W1[8 * 64 + ch0];
    const float w6b = W1[6 * 64 + ch0 + 1], w7b = W1[7 * 64 + ch0 + 1], w8b = W1[8 * 64 + ch0 + 1];
    const float s1a = g1[ch0] * rsqrtf(v1[ch0] + BN_EPS);
    const float o1a = bt1[ch0] - m1[ch0] * s1a;
    const float s1b = g1[ch0 + 1] * rsqrtf(v1[ch0 + 1] + BN_EPS);
    const float o1b = bt1[ch0 + 1] - m1[ch0 + 1] * s1b;

    const int base = blockIdx.x * PTS2;

    // ---- prologue A (wave-split): T_self rows, wave wv covers pl in [wv*8, wv*8+8) ----
#pragma unroll
    for (int q = 0; q < 4; ++q) {
        const int pl = wv * 8 + q * 2 + rsub;
        const unsigned int a = *(const unsigned int*)&B1[(size_t)(base + pl) * 64 + ch0];
        const float ta = fmaf(fmaxf(bflo(a), 0.f), s1a, o1a);
        const float tb = fmaf(fmaxf(bfhi(a), 0.f), s1b, o1b);
        const unsigned int w = (unsigned int)f2bf(ta) | ((unsigned int)f2bf(tb) << 16);
        const int row = pl & 15;
        int byte = row * 128 + ch0 * 2;
        byte ^= (row & 7) << 4;
        *(unsigned int*)(Tl[pl >> 4] + byte) = w;
    }
    __syncthreads();
    // ---- prologue B: S_self = T_self @ W2 -> Ssb (bf16) ----
    {
        f32x4 accS[2][2];
#pragma unroll
        for (int hf = 0; hf < 2; ++hf)
#pragma unroll
            for (int nt = 0; nt < 2; ++nt) accS[hf][nt] = f32x4{0.f, 0.f, 0.f, 0.f};
#pragma unroll
        for (int hf = 0; hf < 2; ++hf)
#pragma unroll
            for (int kt = 0; kt < 2; ++kt) {
                int b0 = lmod * 128 + kt * 64 + lgrp * 16;
                b0 ^= (lmod & 7) << 4;
                const v8s a0 = *(const v8s*)(Tl[hf] + b0);
#pragma unroll
                for (int nt = 0; nt < 2; ++nt)
                    accS[hf][nt] = __builtin_amdgcn_mfma_f32_16x16x32_bf16(a0, Bf2[nt][kt], accS[hf][nt], 0, 0, 0);
            }
#pragma unroll
        for (int hf = 0; hf < 2; ++hf)
#pragma unroll
            for (int nt = 0; nt < 2; ++nt)
#pragma unroll
                for (int reg = 0; reg < 4; ++reg)
                    Ssb[(hf * 16 + lgrp * 4 + reg) * 128 + wv * 32 + nt * 16 + lmod] =
                        f2bf(accS[hf][nt][reg]);
    }
    __syncthreads();

    // ---- build T p=0; prefetch p=1 ----
    {
        const int i = base;
        const float cx = pos[i * 3 + 0], cy = pos[i * 3 + 1], cz = pos[i * 3 + 2];
#pragma unroll
        for (int it = 0; it < 2; ++it) {
            const int m = it * 8 + wv * 2 + rsub;     // 0..15
            const int idx = nbr[i * KNBR + m];
            const unsigned int a = *(const unsigned int*)&B1[(size_t)idx * 64 + ch0];
            const float rx = pos[idx * 3 + 0] - cx;
            const float ry = pos[idx * 3 + 1] - cy;
            const float rz = pos[idx * 3 + 2] - cz;
            float pa = bflo(a);
            pa = fmaf(rx, w6a, pa); pa = fmaf(ry, w7a, pa); pa = fmaf(rz, w8a, pa);
            float pb = bfhi(a);
            pb = fmaf(rx, w6b, pb); pb = fmaf(ry, w7b, pb); pb = fmaf(rz, w8b, pb);
            const float ta = fmaf(fmaxf(pa, 0.f), s1a, o1a);
            const float tb = fmaf(fmaxf(pb, 0.f), s1b, o1b);
            const unsigned int w = (unsigned int)f2bf(ta) | ((unsigned int)f2bf(tb) << 16);
            int byte = m * 128 + ch0 * 2;
            byte ^= (m & 7) << 4;
            *(unsigned int*)(Tl[0] + byte) = w;
        }
    }
    unsigned int aCur[2], aNxt[2];
    float pCx[2], pCy[2], pCz[2], pNx[2], pNy[2], pNz[2];
#pragma unroll
    for (int it = 0; it < 2; ++it) { aCur[it] = 0u; aNxt[it] = 0u; pCx[it]=pCy[it]=pCz[it]=pNx[it]=pNy[it]=pNz[it]=0.f; }
    {
        const int in_ = base + 1;
#pragma unroll
        for (int it = 0; it < 2; ++it) {
            const int m = it * 8 + wv * 2 + rsub;
            const int idx = nbr[in_ * KNBR + m];
            aCur[it] = *(const unsigned int*)&B1[(size_t)idx * 64 + ch0];
            pCx[it] = pos[idx * 3 + 0]; pCy[it] = pos[idx * 3 + 1]; pCz[it] = pos[idx * 3 + 2];
        }
    }
    __syncthreads();

    for (int p = 0; p < PTS2; ++p) {
        const int buf = p & 1;
        if (p < PTS2 - 2) {
            const int in2 = base + p + 2;
#pragma unroll
            for (int it = 0; it < 2; ++it) {
                const int m = it * 8 + wv * 2 + rsub;
                const int idx = nbr[in2 * KNBR + m];
                aNxt[it] = *(const unsigned int*)&B1[(size_t)idx * 64 + ch0];
                pNx[it] = pos[idx * 3 + 0]; pNy[it] = pos[idx * 3 + 1]; pNz[it] = pos[idx * 3 + 2];
            }
        }
        // ---- GEMM (16 neighbor rows) ----
        f32x4 acc0[2];
        acc0[0] = f32x4{0.f, 0.f, 0.f, 0.f};
        acc0[1] = f32x4{0.f, 0.f, 0.f, 0.f};
#pragma unroll
        for (int kt = 0; kt < 2; ++kt) {
            int b0 = lmod * 128 + kt * 64 + lgrp * 16;
            b0 ^= (lmod & 7) << 4;
            const v8s a0 = *(const v8s*)(Tl[buf] + b0);
#pragma unroll
            for (int nt = 0; nt < 2; ++nt)
                acc0[nt] = __builtin_amdgcn_mfma_f32_16x16x32_bf16(a0, Bf2[nt][kt], acc0[nt], 0, 0, 0);
        }
        // ---- epilogue: max over 16 rows + self (bf16 Ssb) -> H tile ----
#pragma unroll
        for (int nt = 0; nt < 2; ++nt) {
            float mv = fmaxf(fmaxf(acc0[nt][0], acc0[nt][1]),
                             fmaxf(acc0[nt][2], acc0[nt][3]));
            mv = fmaxf(mv, __shfl_xor(mv, 16));
            mv = fmaxf(mv, __shfl_xor(mv, 32));
            const float ss = bf2f(Ssb[p * 128 + wv * 32 + nt * 16 + lmod]);
            const float h = fmaxf(fmaxf(mv, ss) + b2c[nt], 0.f);
            if (lgrp == 0) {
                int hb = p * 256 + (wv * 32 + nt * 16 + lmod) * 2;
                hb ^= (p & 7) << 4;
                *(unsigned short*)(Hl + hb) = f2bf(h);
            }
        }
        // ---- build T p+1 ----
        if (p < PTS2 - 1) {
            const int in_ = base + p + 1;
            const float ccx = pos[in_ * 3 + 0], ccy = pos[in_ * 3 + 1], ccz = pos[in_ * 3 + 2];
#pragma unroll
            for (int it = 0; it < 2; ++it) {
                const int m = it * 8 + wv * 2 + rsub;
                const float rx = pCx[it] - ccx, ry = pCy[it] - ccy, rz = pCz[it] - ccz;
                float pa = bflo(aCur[it]);
                pa = fmaf(rx, w6a, pa); pa = fmaf(ry, w7a, pa); pa = fmaf(rz, w8a, pa);
                float pb = bfhi(aCur[it]);
                pb = fmaf(rx, w6b, pb); pb = fmaf(ry, w7b, pb); pb = fmaf(rz, w8b, pb);
                const float ta = fmaf(fmaxf(pa, 0.f), s1a, o1a);
                const float tb = fmaf(fmaxf(pb, 0.f), s1b, o1b);
                const unsigned int w = (unsigned int)f2bf(ta) | ((unsigned int)f2bf(tb) << 16);
                int byte = m * 128 + ch0 * 2;
                byte ^= (m & 7) << 4;
                *(unsigned int*)(Tl[buf ^ 1] + byte) = w;
            }
        }
        __syncthreads();
#pragma unroll
        for (int it = 0; it < 2; ++it) {
            aCur[it] = aNxt[it];
            pCx[it] = pNx[it]; pCy[it] = pNy[it]; pCz[it] = pNz[it];
        }
    }

    // ---- block epilogue: A2[32x128] = H @ W3[0:128] + b3 (bf16 out) ----
    v8s Wf3[2][4];
    float b3c[2];
#pragma unroll
    for (int nt = 0; nt < 2; ++nt) {
        const int col = wv * 32 + nt * 16 + lmod;
        b3c[nt] = b3[col];
#pragma unroll
        for (int kt = 0; kt < 4; ++kt)
#pragma unroll
            for (int j = 0; j < 8; ++j)
                Wf3[nt][kt][j] = (short)f2bf(W3[(kt * 32 + lgrp * 8 + j) * 128 + col]);
    }
    f32x4 accA[2][2];
#pragma unroll
    for (int mt = 0; mt < 2; ++mt)
#pragma unroll
        for (int nt = 0; nt < 2; ++nt) accA[mt][nt] = f32x4{0.f, 0.f, 0.f, 0.f};
#pragma unroll
    for (int kt = 0; kt < 4; ++kt) {
#pragma unroll
        for (int mt = 0; mt < 2; ++mt) {
            int ba = (mt * 16 + lmod) * 256 + kt * 64 + lgrp * 16;
            ba ^= (lmod & 7) << 4;
            const v8s aH = *(const v8s*)(Hl + ba);
#pragma unroll
            for (int nt = 0; nt < 2; ++nt)
                accA[mt][nt] = __builtin_amdgcn_mfma_f32_16x16x32_bf16(aH, Wf3[nt][kt], accA[mt][nt], 0, 0, 0);
        }
    }
#pragma unroll
    for (int mt = 0; mt < 2; ++mt)
#pragma unroll
        for (int nt = 0; nt < 2; ++nt)
#pragma unroll
            for (int reg = 0; reg < 4; ++reg) {
                const int row = base + mt * 16 + lgrp * 4 + reg;
                const int col = wv * 32 + nt * 16 + lmod;
                A2[(size_t)row * 128 + col] = f2bf(accA[mt][nt][reg] + b3c[nt]);
            }
}

// ---------------------------------------------------------------------------
// K4: conv2, self amortized. Per point: 16 neighbor rows (16 MFMA/wave),
// h -> bf16 H2 LDS tile. Block epilogue: Z[32x8] = H2 @ Wc via MFMA (waves
// 0-1) + in-register log_softmax -> out. No per-point classifier/shuffles.
// ---------------------------------------------------------------------------
#define PTS4 32
__global__ __launch_bounds__(256, 2)
void k4_conv2_mfma(const float* __restrict__ pos, const int* __restrict__ nbr,
                   const unsigned short* __restrict__ A2, const float* __restrict__ W3,
                   const float* __restrict__ g2, const float* __restrict__ bt2,
                   const float* __restrict__ m2, const float* __restrict__ v2,
                   const float* __restrict__ W4, const float* __restrict__ b4,
                   const float* __restrict__ Wc, const float* __restrict__ bc,
                   float* __restrict__ out) {
    __shared__ __align__(16) unsigned char Tl[2][16 * 256];  // 8KB
    __shared__ unsigned short Ssb[32 * 256];                 // 16KB (bf16 self scores)
    __shared__ __align__(16) unsigned char H2[32 * 512];     // 16KB (bf16 h tile)

    const int tid  = threadIdx.x;
    const int wv   = tid >> 6;
    const int lane = tid & 63;
    const int lgrp = lane >> 4;
    const int lmod = lane & 15;

    v8s Bf[4][4];
#pragma unroll
    for (int nt = 0; nt < 4; ++nt) {
        const int col = wv * 64 + nt * 16 + lmod;
#pragma unroll
        for (int kt = 0; kt < 4; ++kt)
#pragma unroll
            for (int j = 0; j < 8; ++j)
                Bf[nt][kt][j] = (short)f2bf(W4[(kt * 32 + lgrp * 8 + j) * 256 + col]);
    }
    float b4c[4];
#pragma unroll
    for (int nt = 0; nt < 4; ++nt) b4c[nt] = b4[wv * 64 + nt * 16 + lmod];
    const int ch0 = lane * 2;
    const float bw0a = W3[128 * 128 + ch0],     bw1a = W3[129 * 128 + ch0],     bw2a = W3[130 * 128 + ch0];
    const float bw0b = W3[128 * 128 + ch0 + 1], bw1b = W3[129 * 128 + ch0 + 1], bw2b = W3[130 * 128 + ch0 + 1];
    const float sa = g2[ch0] * rsqrtf(v2[ch0] + BN_EPS);
    const float oa = bt2[ch0] - m2[ch0] * sa;
    const float sb = g2[ch0 + 1] * rsqrtf(v2[ch0 + 1] + BN_EPS);
    const float ob = bt2[ch0 + 1] - m2[ch0 + 1] * sb;

    const int base = blockIdx.x * PTS4;

    // ---- prologue A (wave-split): T_self rows, wave wv covers pl in [wv*8, wv*8+8) ----
#pragma unroll
    for (int r = 0; r < 8; ++r) {
        const int pl = wv * 8 + r;
        const unsigned int a = *(const unsigned int*)&A2[(size_t)(base + pl) * 128 + ch0];
        const float ta = fmaf(fmaxf(bflo(a), 0.f), sa, oa);
        const float tb = fmaf(fmaxf(bfhi(a), 0.f), sb, ob);
        const unsigned int w = (unsigned int)f2bf(ta) | ((unsigned int)f2bf(tb) << 16);
        const int row = pl & 15;
        int byte = row * 256 + ch0 * 2;
        byte ^= (row & 7) << 4;
        *(unsigned int*)(Tl[pl >> 4] + byte) = w;
    }
    __syncthreads();
    // ---- prologue B: S_self = T_self @ W4 -> Ssb (bf16) ----
    {
        f32x4 accS[2][4];
#pragma unroll
        for (int hf = 0; hf < 2; ++hf)
#pragma unroll
            for (int nt = 0; nt < 4; ++nt) accS[hf][nt] = f32x4{0.f, 0.f, 0.f, 0.f};
#pragma unroll
        for (int hf = 0; hf < 2; ++hf)
#pragma unroll
            for (int kt = 0; kt < 4; ++kt) {
                int b0 = lmod * 256 + kt * 64 + lgrp * 16;
                b0 ^= (lmod & 7) << 4;
                const v8s a0 = *(const v8s*)(Tl[hf] + b0);
#pragma unroll
                for (int nt = 0; nt < 4; ++nt)
                    accS[hf][nt] = __builtin_amdgcn_mfma_f32_16x16x32_bf16(a0, Bf[nt][kt], accS[hf][nt], 0, 0, 0);
            }
#pragma unroll
        for (int hf = 0; hf < 2; ++hf)
#pragma unroll
            for (int nt = 0; nt < 4; ++nt)
#pragma unroll
                for (int reg = 0; reg < 4; ++reg)
                    Ssb[(hf * 16 + lgrp * 4 + reg) * 256 + wv * 64 + nt * 16 + lmod] =
                        f2bf(accS[hf][nt][reg]);
    }
    __syncthreads();

    // ---- build T p=0; prefetch p=1 ----
    {
        const int i = base;
        const float cx = pos[i * 3 + 0], cy = pos[i * 3 + 1], cz = pos[i * 3 + 2];
#pragma unroll
        for (int it = 0; it < 4; ++it) {
            const int m = it * 4 + wv;                 // 0..15
            const int idx = nbr[i * KNBR + m];
            const unsigned int a = *(const unsigned int*)&A2[(size_t)idx * 128 + ch0];
            const float rx = pos[idx * 3 + 0] - cx;
            const float ry = pos[idx * 3 + 1] - cy;
            const float rz = pos[idx * 3 + 2] - cz;
            float pa = bflo(a);
            pa = fmaf(rx, bw0a, pa); pa = fmaf(ry, bw1a, pa); pa = fmaf(rz, bw2a, pa);
            float pb = bfhi(a);
            pb = fmaf(rx, bw0b, pb); pb = fmaf(ry, bw1b, pb); pb = fmaf(rz, bw2b, pb);
            const float ta = fmaf(fmaxf(pa, 0.f), sa, oa);
            const float tb = fmaf(fmaxf(pb, 0.f), sb, ob);
            const unsigned int w = (unsigned int)f2bf(ta) | ((unsigned int)f2bf(tb) << 16);
            int byte = m * 256 + ch0 * 2;
            byte ^= (m & 7) << 4;
            *(unsigned int*)(Tl[0] + byte) = w;
        }
    }
    unsigned int aCur[4], aNxt[4];
    float pCx[4], pCy[4], pCz[4], pNx[4], pNy[4], pNz[4];
#pragma unroll
    for (int it = 0; it < 4; ++it) { aCur[it] = 0u; aNxt[it] = 0u; pCx[it]=pCy[it]=pCz[it]=pNx[it]=pNy[it]=pNz[it]=0.f; }
    {
        const int in_ = base + 1;
#pragma unroll
        for (int it = 0; it < 4; ++it) {
            const int m = it * 4 + wv;
            const int idx = nbr[in_ * KNBR + m];
            aCur[it] = *(const unsigned int*)&A2[(size_t)idx * 128 + ch0];
            pCx[it] = pos[idx * 3 + 0]; pCy[it] = pos[idx * 3 + 1]; pCz[it] = pos[idx * 3 + 2];
        }
    }
    __syncthreads();

    for (int p = 0; p < PTS4; ++p) {
        const int buf = p & 1;
        if (p < PTS4 - 2) {
            const int in2 = base + p + 2;
#pragma unroll
            for (int it = 0; it < 4; ++it) {
                const int m = it * 4 + wv;
                const int idx = nbr[in2 * KNBR + m];
                aNxt[it] = *(const unsigned int*)&A2[(size_t)idx * 128 + ch0];
                pNx[it] = pos[idx * 3 + 0]; pNy[it] = pos[idx * 3 + 1]; pNz[it] = pos[idx * 3 + 2];
            }
        }
        // ---- GEMM (16 neighbor rows) ----
        f32x4 acc0[4];
#pragma unroll
        for (int nt = 0; nt < 4; ++nt) acc0[nt] = f32x4{0.f, 0.f, 0.f, 0.f};
#pragma unroll
        for (int kt = 0; kt < 4; ++kt) {
            int b0 = lmod * 256 + kt * 64 + lgrp * 16;
            b0 ^= (lmod & 7) << 4;
            const v8s a0 = *(const v8s*)(Tl[buf] + b0);
#pragma unroll
            for (int nt = 0; nt < 4; ++nt)
                acc0[nt] = __builtin_amdgcn_mfma_f32_16x16x32_bf16(a0, Bf[nt][kt], acc0[nt], 0, 0, 0);
        }
        // ---- epilogue: max + self -> h -> H2 (bf16) ----
#pragma unroll
        for (int nt = 0; nt < 4; ++nt) {
            float mv = fmaxf(fmaxf(acc0[nt][0], acc0[nt][1]),
                             fmaxf(acc0[nt][2], acc0[nt][3]));
            mv = fmaxf(mv, __shfl_xor(mv, 16));
            mv = fmaxf(mv, __shfl_xor(mv, 32));
            const float ss = bf2f(Ssb[p * 256 + wv * 64 + nt * 16 + lmod]);
            const float h = fmaxf(fmaxf(mv, ss) + b4c[nt], 0.f);
            if (lgrp == 0) {
                int hb = p * 512 + (wv * 64 + nt * 16 + lmod) * 2;
                hb ^= (p & 7) << 4;
                *(unsigned short*)(H2 + hb) = f2bf(h);
            }
        }
        // ---- build T p+1 ----
        if (p < PTS4 - 1) {
            const int in_ = base + p + 1;
            const float ccx = pos[in_ * 3 + 0], ccy = pos[in_ * 3 + 1], ccz = pos[in_ * 3 + 2];
#pragma unroll
            for (int it = 0; it < 4; ++it) {
                const int m = it * 4 + wv;
                const float rx = pCx[it] - ccx, ry = pCy[it] - ccy, rz = pCz[it] - ccz;
                float pa = bflo(aCur[it]);
                pa = fmaf(rx, bw0a, pa); pa = fmaf(ry, bw1a, pa); pa = fmaf(rz, bw2a, pa);
                float pb = bfhi(aCur[it]);
                pb = fmaf(rx, bw0b, pb); pb = fmaf(ry, bw1b, pb); pb = fmaf(rz, bw2b, pb);
                const float ta = fmaf(fmaxf(pa, 0.f), sa, oa);
                const float tb = fmaf(fmaxf(pb, 0.f), sb, ob);
                const unsigned int w = (unsigned int)f2bf(ta) | ((unsigned int)f2bf(tb) << 16);
                int byte = m * 256 + ch0 * 2;
                byte ^= (m & 7) << 4;
                *(unsigned int*)(Tl[buf ^ 1] + byte) = w;
            }
        }
        __syncthreads();
#pragma unroll
        for (int it = 0; it < 4; ++it) {
            aCur[it] = aNxt[it];
            pCx[it] = pNx[it]; pCy[it] = pNy[it]; pCz[it] = pNz[it];
        }
    }

    // ---- block epilogue: Z[32x8] = H2 @ Wc + bc, log_softmax -> out ----
    // (H2 complete after the loop's final barrier.) Waves 0-1 each do 16 rows.
    if (wv < 2) {
        v8s wcf[8];
#pragma unroll
        for (int kt = 0; kt < 8; ++kt)
#pragma unroll
            for (int j = 0; j < 8; ++j)
                wcf[kt][j] = (lmod < 8)
                    ? (short)f2bf(Wc[(kt * 32 + lgrp * 8 + j) * 8 + lmod])
                    : (short)0;
        f32x4 accZ = f32x4{0.f, 0.f, 0.f, 0.f};
        const int row = wv * 16 + lmod;
#pragma unroll
        for (int kt = 0; kt < 8; ++kt) {
            int ba = row * 512 + kt * 64 + lgrp * 16;
            ba ^= (row & 7) << 4;
            const v8s aH = *(const v8s*)(H2 + ba);
            accZ = __builtin_amdgcn_mfma_f32_16x16x32_bf16(aH, wcf[kt], accZ, 0, 0, 0);
        }
        const float bcv = (lmod < 8) ? bc[lmod] : 0.f;
#pragma unroll
        for (int reg = 0; reg < 4; ++reg) {
            const float z = accZ[reg] + bcv;
            float mz = z;
            mz = fmaxf(mz, __shfl_xor(mz, 1));
            mz = fmaxf(mz, __shfl_xor(mz, 2));
            mz = fmaxf(mz, __shfl_xor(mz, 4));
            const float e = expf(z - mz);
            float se = e;
            se += __shfl_xor(se, 1);
            se += __shfl_xor(se, 2);
            se += __shfl_xor(se, 4);
            if (lmod < 8)
                out[(size_t)(base + wv * 16 + lgrp * 4 + reg) * 8 + lmod] = z - mz - logf(se);
        }
    }
}

extern "C" void kernel_launch(void* const* d_in, const int* in_sizes, int n_in,
                              void* d_out, int out_size, void* d_ws, size_t ws_size,
                              hipStream_t stream) {
    const float* pos = (const float*)d_in[0];
    const int*   nbr = (const int*)d_in[1];
    const float* W1  = (const float*)d_in[2];
    const float* b1  = (const float*)d_in[3];
    const float* g1  = (const float*)d_in[4];
    const float* bt1 = (const float*)d_in[5];
    const float* m1  = (const float*)d_in[6];
    const float* v1  = (const float*)d_in[7];
    const float* W2  = (const float*)d_in[8];
    const float* b2  = (const float*)d_in[9];
    const float* W3  = (const float*)d_in[10];
    const float* b3  = (const float*)d_in[11];
    const float* g2  = (const float*)d_in[12];
    const float* bt2 = (const float*)d_in[13];
    const float* m2  = (const float*)d_in[14];
    const float* v2  = (const float*)d_in[15];
    const float* W4  = (const float*)d_in[16];
    const float* b4  = (const float*)d_in[17];
    const float* Wc  = (const float*)d_in[18];
    const float* bc  = (const float*)d_in[19];
    float* out = (float*)d_out;

    unsigned short* B1 = (unsigned short*)d_ws;       // 40000*64*2  = 5.12 MB
    unsigned short* A2 = B1 + (size_t)NPTS * 64;      // 40000*128*2 = 10.24 MB

    k1_b1<<<NPTS / 4, 256, 0, stream>>>(pos, nbr, W1, b1, B1);
    k2_conv1_mfma<<<NPTS / PTS2, 256, 0, stream>>>(pos, nbr, B1, W1, g1, bt1, m1, v1,
                                                   W2, b2, W3, b3, A2);
    k4_conv2_mfma<<<NPTS / PTS4, 256, 0, stream>>>(pos, nbr, A2, W3, g2, bt2, m2, v2,
                                                   W4, b4, Wc, bc, out);
}

// Round 13
// 319.812 us; speedup vs baseline: 1.0086x; 1.0086x over previous
//
#include <hip/hip_runtime.h>
#include <math.h>

#define NPTS 40000
#define KNBR 16
#define BN_EPS 1e-5f

typedef __attribute__((ext_vector_type(8))) short v8s;
typedef __attribute__((ext_vector_type(4))) float f32x4;

__device__ __forceinline__ unsigned short f2bf(float f) {
    union { float f; unsigned int u; } c; c.f = f;
    unsigned int u = c.u + 0x7fffu + ((c.u >> 16) & 1u);   // RNE
    return (unsigned short)(u >> 16);
}
__device__ __forceinline__ float bflo(unsigned int u) {
    union { unsigned int u; float f; } c; c.u = u << 16; return c.f;
}
__device__ __forceinline__ float bfhi(unsigned int u) {
    union { unsigned int u; float f; } c; c.u = u & 0xffff0000u; return c.f;
}
__device__ __forceinline__ float bf2f(unsigned short u) {
    union { unsigned int u; float f; } c; c.u = ((unsigned int)u) << 16; return c.f;
}

// ---------------------------------------------------------------------------
// K1: per-point normals + B1[j][64] = [pos_j, normal_j] @ W1[0:6] + b1 (bf16)
// ---------------------------------------------------------------------------
__global__ __launch_bounds__(256, 4)
void k1_b1(const float* __restrict__ pos, const int* __restrict__ nbr,
           const float* __restrict__ W1, const float* __restrict__ b1,
           unsigned short* __restrict__ B1) {
    int p = blockIdx.x * 4 + (threadIdx.x >> 6);
    int k = threadIdx.x & 63;
    float px = pos[p * 3 + 0], py = pos[p * 3 + 1], pz = pos[p * 3 + 2];
    int n0 = nbr[p * KNBR + 0], n1 = nbr[p * KNBR + 1];
    float ax = pos[n0 * 3 + 0] - px, ay = pos[n0 * 3 + 1] - py, az = pos[n0 * 3 + 2] - pz;
    float bx = pos[n1 * 3 + 0] - px, by = pos[n1 * 3 + 1] - py, bz = pos[n1 * 3 + 2] - pz;
    float cx = ay * bz - az * by;
    float cy = az * bx - ax * bz;
    float cz = ax * by - ay * bx;
    float nrm = sqrtf(cx * cx + cy * cy + cz * cz);
    float inv = 1.0f / fmaxf(nrm, 1e-12f);
    float ux, uy, uz;
    if (nrm > 0.0f) { ux = cx * inv; uy = cy * inv; uz = cz * inv; }
    else            { ux = 0.0f;     uy = 0.0f;     uz = 1.0f;     }
    float acc = b1[k];
    acc = fmaf(px, W1[0 * 64 + k], acc);
    acc = fmaf(py, W1[1 * 64 + k], acc);
    acc = fmaf(pz, W1[2 * 64 + k], acc);
    acc = fmaf(ux, W1[3 * 64 + k], acc);
    acc = fmaf(uy, W1[4 * 64 + k], acc);
    acc = fmaf(uz, W1[5 * 64 + k], acc);
    B1[p * 64 + k] = f2bf(acc);
}

// ---------------------------------------------------------------------------
// K2: conv1 + k3 folded. M=64 tile: 4 points/iter (8 iters). Wave wv builds
// rows [wv*16,+16) = messages of point g*4+wv; prefetch consumed same iter
// (nothing in flight at barrier -> cheap drain). Self rows amortized (Ssb).
// ---------------------------------------------------------------------------
#define PTS2 32
#define NG2 8
__global__ __launch_bounds__(256, 2)
void k2_conv1_mfma(const float* __restrict__ pos, const int* __restrict__ nbr,
                   const unsigned short* __restrict__ B1, const float* __restrict__ W1,
                   const float* __restrict__ g1, const float* __restrict__ bt1,
                   const float* __restrict__ m1, const float* __restrict__ v1,
                   const float* __restrict__ W2, const float* __restrict__ b2,
                   const float* __restrict__ W3, const float* __restrict__ b3,
                   unsigned short* __restrict__ A2) {
    __shared__ __align__(16) unsigned char Tl[2][64 * 128];  // 8KB each
    __shared__ __align__(16) unsigned char Hl[32 * 256];     // 8KB
    __shared__ unsigned short Ssb[32 * 128];                 // 8KB

    const int tid  = threadIdx.x;
    const int wv   = tid >> 6;
    const int lane = tid & 63;
    const int lgrp = lane >> 4;
    const int lmod = lane & 15;

    v8s Bf2[2][2];
    float b2c[2];
#pragma unroll
    for (int nt = 0; nt < 2; ++nt) {
        const int col = wv * 32 + nt * 16 + lmod;
        b2c[nt] = b2[col];
#pragma unroll
        for (int kt = 0; kt < 2; ++kt)
#pragma unroll
            for (int j = 0; j < 8; ++j)
                Bf2[nt][kt][j] = (short)f2bf(W2[(kt * 32 + lgrp * 8 + j) * 128 + col]);
    }
    const int ch = lane;                        // one input channel per lane
    const float w6 = W1[6 * 64 + ch], w7 = W1[7 * 64 + ch], w8 = W1[8 * 64 + ch];
    const float s1 = g1[ch] * rsqrtf(v1[ch] + BN_EPS);
    const float o1 = bt1[ch] - m1[ch] * s1;

    const int base = blockIdx.x * PTS2;

    // ---- prologue A: self rows 0..31 -> Tl[0] (wave-split, 8 rows each) ----
#pragma unroll
    for (int r = 0; r < 8; ++r) {
        const int pl = wv * 8 + r;
        const float bv = bf2f(B1[(size_t)(base + pl) * 64 + ch]);
        const float t = fmaf(fmaxf(bv, 0.f), s1, o1);
        int byte = pl * 128 + ch * 2;
        byte ^= (pl & 7) << 4;
        *(unsigned short*)(Tl[0] + byte) = f2bf(t);
    }
    __syncthreads();
    // ---- prologue B: Ssb = self @ W2 (bf16) ----
    {
        f32x4 accS[2][2];
#pragma unroll
        for (int hf = 0; hf < 2; ++hf)
#pragma unroll
            for (int nt = 0; nt < 2; ++nt) accS[hf][nt] = f32x4{0.f, 0.f, 0.f, 0.f};
#pragma unroll
        for (int hf = 0; hf < 2; ++hf)
#pragma unroll
            for (int kt = 0; kt < 2; ++kt) {
                const int row = hf * 16 + lmod;
                int b0 = row * 128 + kt * 64 + lgrp * 16;
                b0 ^= (row & 7) << 4;
                const v8s a0 = *(const v8s*)(Tl[0] + b0);
#pragma unroll
                for (int nt = 0; nt < 2; ++nt)
                    accS[hf][nt] = __builtin_amdgcn_mfma_f32_16x16x32_bf16(a0, Bf2[nt][kt], accS[hf][nt], 0, 0, 0);
            }
#pragma unroll
        for (int hf = 0; hf < 2; ++hf)
#pragma unroll
            for (int nt = 0; nt < 2; ++nt)
#pragma unroll
                for (int reg = 0; reg < 4; ++reg)
                    Ssb[(hf * 16 + lgrp * 4 + reg) * 128 + wv * 32 + nt * 16 + lmod] =
                        f2bf(accS[hf][nt][reg]);
    }
    __syncthreads();                             // Ssb ready; Tl[0] reads done

    // ---- build T for group 0 (wave wv -> rows [wv*16,+16), point base+wv) ----
    {
        const int i0 = base + wv;
        const float cx = pos[i0 * 3 + 0], cy = pos[i0 * 3 + 1], cz = pos[i0 * 3 + 2];
#pragma unroll
        for (int m = 0; m < 16; ++m) {
            int idx = nbr[i0 * KNBR + m];
            idx = __builtin_amdgcn_readfirstlane(idx);
            const float bv = bf2f(B1[(size_t)idx * 64 + ch]);
            const float rx = pos[idx * 3 + 0] - cx;
            const float ry = pos[idx * 3 + 1] - cy;
            const float rz = pos[idx * 3 + 2] - cz;
            float pre = bv;
            pre = fmaf(rx, w6, pre); pre = fmaf(ry, w7, pre); pre = fmaf(rz, w8, pre);
            const float t = fmaf(fmaxf(pre, 0.f), s1, o1);
            const int row = wv * 16 + m;
            int byte = row * 128 + ch * 2;
            byte ^= (row & 7) << 4;
            *(unsigned short*)(Tl[0] + byte) = f2bf(t);
        }
    }
    __syncthreads();

    unsigned short aN[16];
    int idxN[16];
    float cNx = 0.f, cNy = 0.f, cNz = 0.f;
    for (int g = 0; g < NG2; ++g) {
        const int buf = g & 1;
        // ---- prefetch group g+1 (consumed at this iter's build) ----
        if (g < NG2 - 1) {
            const int iN = base + (g + 1) * 4 + wv;
            cNx = pos[iN * 3 + 0]; cNy = pos[iN * 3 + 1]; cNz = pos[iN * 3 + 2];
#pragma unroll
            for (int m = 0; m < 16; ++m) {
                int idx = nbr[iN * KNBR + m];
                idx = __builtin_amdgcn_readfirstlane(idx);
                idxN[m] = idx;
                aN[m] = B1[(size_t)idx * 64 + ch];
            }
        }
        // ---- GEMM + epilogue per row-block (point g*4+rb) ----
#pragma unroll
        for (int rb = 0; rb < 4; ++rb) {
            f32x4 acc[2];
            acc[0] = f32x4{0.f, 0.f, 0.f, 0.f};
            acc[1] = f32x4{0.f, 0.f, 0.f, 0.f};
#pragma unroll
            for (int kt = 0; kt < 2; ++kt) {
                const int row = rb * 16 + lmod;
                int b0 = row * 128 + kt * 64 + lgrp * 16;
                b0 ^= (row & 7) << 4;
                const v8s a0 = *(const v8s*)(Tl[buf] + b0);
#pragma unroll
                for (int nt = 0; nt < 2; ++nt)
                    acc[nt] = __builtin_amdgcn_mfma_f32_16x16x32_bf16(a0, Bf2[nt][kt], acc[nt], 0, 0, 0);
            }
            const int pl = g * 4 + rb;
#pragma unroll
            for (int nt = 0; nt < 2; ++nt) {
                float mv = fmaxf(fmaxf(acc[nt][0], acc[nt][1]),
                                 fmaxf(acc[nt][2], acc[nt][3]));
                mv = fmaxf(mv, __shfl_xor(mv, 16));
                mv = fmaxf(mv, __shfl_xor(mv, 32));
                const float ss = bf2f(Ssb[pl * 128 + wv * 32 + nt * 16 + lmod]);
                const float h = fmaxf(fmaxf(mv, ss) + b2c[nt], 0.f);
                if (lgrp == 0) {
                    int hb = pl * 256 + (wv * 32 + nt * 16 + lmod) * 2;
                    hb ^= (pl & 7) << 4;
                    *(unsigned short*)(Hl + hb) = f2bf(h);
                }
            }
        }
        // ---- build T for g+1 into Tl[buf^1] ----
        if (g < NG2 - 1) {
#pragma unroll
            for (int m = 0; m < 16; ++m) {
                const int idx = idxN[m];
                const float rx = pos[idx * 3 + 0] - cNx;
                const float ry = pos[idx * 3 + 1] - cNy;
                const float rz = pos[idx * 3 + 2] - cNz;
                float pre = bf2f(aN[m]);
                pre = fmaf(rx, w6, pre); pre = fmaf(ry, w7, pre); pre = fmaf(rz, w8, pre);
                const float t = fmaf(fmaxf(pre, 0.f), s1, o1);
                const int row = wv * 16 + m;
                int byte = row * 128 + ch * 2;
                byte ^= (row & 7) << 4;
                *(unsigned short*)(Tl[buf ^ 1] + byte) = f2bf(t);
            }
        }
        __syncthreads();
    }

    // ---- block epilogue: A2[32x128] = Hl @ W3[0:128] + b3 (bf16 out) ----
    v8s Wf3[2][4];
    float b3c[2];
#pragma unroll
    for (int nt = 0; nt < 2; ++nt) {
        const int col = wv * 32 + nt * 16 + lmod;
        b3c[nt] = b3[col];
#pragma unroll
        for (int kt = 0; kt < 4; ++kt)
#pragma unroll
            for (int j = 0; j < 8; ++j)
                Wf3[nt][kt][j] = (short)f2bf(W3[(kt * 32 + lgrp * 8 + j) * 128 + col]);
    }
    f32x4 accA[2][2];
#pragma unroll
    for (int mt = 0; mt < 2; ++mt)
#pragma unroll
        for (int nt = 0; nt < 2; ++nt) accA[mt][nt] = f32x4{0.f, 0.f, 0.f, 0.f};
#pragma unroll
    for (int kt = 0; kt < 4; ++kt) {
#pragma unroll
        for (int mt = 0; mt < 2; ++mt) {
            int ba = (mt * 16 + lmod) * 256 + kt * 64 + lgrp * 16;
            ba ^= (lmod & 7) << 4;
            const v8s aH = *(const v8s*)(Hl + ba);
#pragma unroll
            for (int nt = 0; nt < 2; ++nt)
                accA[mt][nt] = __builtin_amdgcn_mfma_f32_16x16x32_bf16(aH, Wf3[nt][kt], accA[mt][nt], 0, 0, 0);
        }
    }
#pragma unroll
    for (int mt = 0; mt < 2; ++mt)
#pragma unroll
        for (int nt = 0; nt < 2; ++nt)
#pragma unroll
            for (int reg = 0; reg < 4; ++reg) {
                const int row = base + mt * 16 + lgrp * 4 + reg;
                const int col = wv * 32 + nt * 16 + lmod;
                A2[(size_t)row * 128 + col] = f2bf(accA[mt][nt][reg] + b3c[nt]);
            }
}

// ---------------------------------------------------------------------------
// K4: conv2, M=64 tile (4 points/iter, 8 iters). Wave wv builds rows of
// point g*4+wv; same-iter prefetch consumption. Self amortized (Ssb).
// Classifier partials -> Z (global); log_softmax in k5. Wc read from L1.
// ---------------------------------------------------------------------------
#define PTS4 32
#define NG4 8
__global__ __launch_bounds__(256, 2)
void k4_conv2_mfma(const float* __restrict__ pos, const int* __restrict__ nbr,
                   const unsigned short* __restrict__ A2, const float* __restrict__ W3,
                   const float* __restrict__ g2, const float* __restrict__ bt2,
                   const float* __restrict__ m2, const float* __restrict__ v2,
                   const float* __restrict__ W4, const float* __restrict__ b4,
                   const float* __restrict__ Wc,
                   float* __restrict__ Z) {
    __shared__ __align__(16) unsigned char Tl[2][64 * 256];  // 16KB each
    __shared__ unsigned short Ssb[32 * 256];                 // 16KB

    const int tid  = threadIdx.x;
    const int wv   = tid >> 6;
    const int lane = tid & 63;
    const int lgrp = lane >> 4;
    const int lmod = lane & 15;

    v8s Bf[4][4];
#pragma unroll
    for (int nt = 0; nt < 4; ++nt) {
        const int col = wv * 64 + nt * 16 + lmod;
#pragma unroll
        for (int kt = 0; kt < 4; ++kt)
#pragma unroll
            for (int j = 0; j < 8; ++j)
                Bf[nt][kt][j] = (short)f2bf(W4[(kt * 32 + lgrp * 8 + j) * 256 + col]);
    }
    float b4c[4];
#pragma unroll
    for (int nt = 0; nt < 4; ++nt) b4c[nt] = b4[wv * 64 + nt * 16 + lmod];
    const int ch0 = lane * 2;
    const float bw0a = W3[128 * 128 + ch0],     bw1a = W3[129 * 128 + ch0],     bw2a = W3[130 * 128 + ch0];
    const float bw0b = W3[128 * 128 + ch0 + 1], bw1b = W3[129 * 128 + ch0 + 1], bw2b = W3[130 * 128 + ch0 + 1];
    const float sa = g2[ch0] * rsqrtf(v2[ch0] + BN_EPS);
    const float oa = bt2[ch0] - m2[ch0] * sa;
    const float sb = g2[ch0 + 1] * rsqrtf(v2[ch0 + 1] + BN_EPS);
    const float ob = bt2[ch0 + 1] - m2[ch0 + 1] * sb;

    const int base = blockIdx.x * PTS4;

    // ---- prologue A: self rows 0..31 -> Tl[0] (wave-split) ----
#pragma unroll
    for (int r = 0; r < 8; ++r) {
        const int pl = wv * 8 + r;
        const unsigned int a = *(const unsigned int*)&A2[(size_t)(base + pl) * 128 + ch0];
        const float ta = fmaf(fmaxf(bflo(a), 0.f), sa, oa);
        const float tb = fmaf(fmaxf(bfhi(a), 0.f), sb, ob);
        const unsigned int w = (unsigned int)f2bf(ta) | ((unsigned int)f2bf(tb) << 16);
        int byte = pl * 256 + ch0 * 2;
        byte ^= (pl & 7) << 4;
        *(unsigned int*)(Tl[0] + byte) = w;
    }
    __syncthreads();
    // ---- prologue B: Ssb = self @ W4 (bf16) ----
    {
        f32x4 accS[2][4];
#pragma unroll
        for (int hf = 0; hf < 2; ++hf)
#pragma unroll
            for (int nt = 0; nt < 4; ++nt) accS[hf][nt] = f32x4{0.f, 0.f, 0.f, 0.f};
#pragma unroll
        for (int hf = 0; hf < 2; ++hf)
#pragma unroll
            for (int kt = 0; kt < 4; ++kt) {
                const int row = hf * 16 + lmod;
                int b0 = row * 256 + kt * 64 + lgrp * 16;
                b0 ^= (row & 7) << 4;
                const v8s a0 = *(const v8s*)(Tl[0] + b0);
#pragma unroll
                for (int nt = 0; nt < 4; ++nt)
                    accS[hf][nt] = __builtin_amdgcn_mfma_f32_16x16x32_bf16(a0, Bf[nt][kt], accS[hf][nt], 0, 0, 0);
            }
#pragma unroll
        for (int hf = 0; hf < 2; ++hf)
#pragma unroll
            for (int nt = 0; nt < 4; ++nt)
#pragma unroll
                for (int reg = 0; reg < 4; ++reg)
                    Ssb[(hf * 16 + lgrp * 4 + reg) * 256 + wv * 64 + nt * 16 + lmod] =
                        f2bf(accS[hf][nt][reg]);
    }
    __syncthreads();

    // ---- build T for group 0 ----
    {
        const int i0 = base + wv;
        const float cx = pos[i0 * 3 + 0], cy = pos[i0 * 3 + 1], cz = pos[i0 * 3 + 2];
#pragma unroll
        for (int m = 0; m < 16; ++m) {
            int idx = nbr[i0 * KNBR + m];
            idx = __builtin_amdgcn_readfirstlane(idx);
            const unsigned int a = *(const unsigned int*)&A2[(size_t)idx * 128 + ch0];
            const float rx = pos[idx * 3 + 0] - cx;
            const float ry = pos[idx * 3 + 1] - cy;
            const float rz = pos[idx * 3 + 2] - cz;
            float pa = bflo(a);
            pa = fmaf(rx, bw0a, pa); pa = fmaf(ry, bw1a, pa); pa = fmaf(rz, bw2a, pa);
            float pb = bfhi(a);
            pb = fmaf(rx, bw0b, pb); pb = fmaf(ry, bw1b, pb); pb = fmaf(rz, bw2b, pb);
            const float ta = fmaf(fmaxf(pa, 0.f), sa, oa);
            const float tb = fmaf(fmaxf(pb, 0.f), sb, ob);
            const unsigned int w = (unsigned int)f2bf(ta) | ((unsigned int)f2bf(tb) << 16);
            const int row = wv * 16 + m;
            int byte = row * 256 + ch0 * 2;
            byte ^= (row & 7) << 4;
            *(unsigned int*)(Tl[0] + byte) = w;
        }
    }
    __syncthreads();

    unsigned int aN[16];
    int idxN[16];
    float cNx = 0.f, cNy = 0.f, cNz = 0.f;
    for (int g = 0; g < NG4; ++g) {
        const int buf = g & 1;
        // ---- prefetch group g+1 ----
        if (g < NG4 - 1) {
            const int iN = base + (g + 1) * 4 + wv;
            cNx = pos[iN * 3 + 0]; cNy = pos[iN * 3 + 1]; cNz = pos[iN * 3 + 2];
#pragma unroll
            for (int m = 0; m < 16; ++m) {
                int idx = nbr[iN * KNBR + m];
                idx = __builtin_amdgcn_readfirstlane(idx);
                idxN[m] = idx;
                aN[m] = *(const unsigned int*)&A2[(size_t)idx * 128 + ch0];
            }
        }
        // ---- GEMM + epilogue per row-block (point g*4+rb) ----
#pragma unroll
        for (int rb = 0; rb < 4; ++rb) {
            f32x4 acc[4];
#pragma unroll
            for (int nt = 0; nt < 4; ++nt) acc[nt] = f32x4{0.f, 0.f, 0.f, 0.f};
#pragma unroll
            for (int kt = 0; kt < 4; ++kt) {
                const int row = rb * 16 + lmod;
                int b0 = row * 256 + kt * 64 + lgrp * 16;
                b0 ^= (row & 7) << 4;
                const v8s a0 = *(const v8s*)(Tl[buf] + b0);
#pragma unroll
                for (int nt = 0; nt < 4; ++nt)
                    acc[nt] = __builtin_amdgcn_mfma_f32_16x16x32_bf16(a0, Bf[nt][kt], acc[nt], 0, 0, 0);
            }
            const int pl = g * 4 + rb;
            float part[8];
#pragma unroll
            for (int c = 0; c < 8; ++c) part[c] = 0.f;
#pragma unroll
            for (int nt = 0; nt < 4; ++nt) {
                float mv = fmaxf(fmaxf(acc[nt][0], acc[nt][1]),
                                 fmaxf(acc[nt][2], acc[nt][3]));
                mv = fmaxf(mv, __shfl_xor(mv, 16));
                mv = fmaxf(mv, __shfl_xor(mv, 32));
                const float ss = bf2f(Ssb[pl * 256 + wv * 64 + nt * 16 + lmod]);
                const float h = fmaxf(fmaxf(mv, ss) + b4c[nt], 0.f);
                const int col = wv * 64 + nt * 16 + lmod;
                const float4 wc0 = *(const float4*)&Wc[col * 8 + 0];
                const float4 wc1 = *(const float4*)&Wc[col * 8 + 4];
                part[0] = fmaf(h, wc0.x, part[0]); part[1] = fmaf(h, wc0.y, part[1]);
                part[2] = fmaf(h, wc0.z, part[2]); part[3] = fmaf(h, wc0.w, part[3]);
                part[4] = fmaf(h, wc1.x, part[4]); part[5] = fmaf(h, wc1.y, part[5]);
                part[6] = fmaf(h, wc1.z, part[6]); part[7] = fmaf(h, wc1.w, part[7]);
            }
#pragma unroll
            for (int c = 0; c < 8; ++c) {
                part[c] += __shfl_xor(part[c], 1);
                part[c] += __shfl_xor(part[c], 2);
                part[c] += __shfl_xor(part[c], 4);
                part[c] += __shfl_xor(part[c], 8);
            }
            if (lane == 0) {
#pragma unroll
                for (int c = 0; c < 8; ++c)
                    Z[(size_t)(base + pl) * 32 + wv * 8 + c] = part[c];
            }
        }
        // ---- build T for g+1 into Tl[buf^1] ----
        if (g < NG4 - 1) {
#pragma unroll
            for (int m = 0; m < 16; ++m) {
                const int idx = idxN[m];
                const float rx = pos[idx * 3 + 0] - cNx;
                const float ry = pos[idx * 3 + 1] - cNy;
                const float rz = pos[idx * 3 + 2] - cNz;
                float pa = bflo(aN[m]);
                pa = fmaf(rx, bw0a, pa); pa = fmaf(ry, bw1a, pa); pa = fmaf(rz, bw2a, pa);
                float pb = bfhi(aN[m]);
                pb = fmaf(rx, bw0b, pb); pb = fmaf(ry, bw1b, pb); pb = fmaf(rz, bw2b, pb);
                const float ta = fmaf(fmaxf(pa, 0.f), sa, oa);
                const float tb = fmaf(fmaxf(pb, 0.f), sb, ob);
                const unsigned int w = (unsigned int)f2bf(ta) | ((unsigned int)f2bf(tb) << 16);
                const int row = wv * 16 + m;
                int byte = row * 256 + ch0 * 2;
                byte ^= (row & 7) << 4;
                *(unsigned int*)(Tl[buf ^ 1] + byte) = w;
            }
        }
        __syncthreads();
    }
}

// ---------------------------------------------------------------------------
// K5: out[i] = log_softmax( sum_w Z[i][w] + bc )
// ---------------------------------------------------------------------------
__global__ __launch_bounds__(256, 4)
void k5_softmax(const float* __restrict__ Z, const float* __restrict__ bc,
                float* __restrict__ out) {
    const int i = blockIdx.x * 256 + threadIdx.x;
    if (i >= NPTS) return;
    float z[8];
#pragma unroll
    for (int c = 0; c < 8; ++c) z[c] = bc[c];
#pragma unroll
    for (int w = 0; w < 4; ++w) {
        const float4 a = *(const float4*)&Z[(size_t)i * 32 + w * 8 + 0];
        const float4 b = *(const float4*)&Z[(size_t)i * 32 + w * 8 + 4];
        z[0] += a.x; z[1] += a.y; z[2] += a.z; z[3] += a.w;
        z[4] += b.x; z[5] += b.y; z[6] += b.z; z[7] += b.w;
    }
    float mz = z[0];
#pragma unroll
    for (int c = 1; c < 8; ++c) mz = fmaxf(mz, z[c]);
    float se = 0.f;
#pragma unroll
    for (int c = 0; c < 8; ++c) se += expf(z[c] - mz);
    const float lse = mz + logf(se);
#pragma unroll
    for (int c = 0; c < 8; ++c) out[(size_t)i * 8 + c] = z[c] - lse;
}

extern "C" void kernel_launch(void* const* d_in, const int* in_sizes, int n_in,
                              void* d_out, int out_size, void* d_ws, size_t ws_size,
                              hipStream_t stream) {
    const float* pos = (const float*)d_in[0];
    const int*   nbr = (const int*)d_in[1];
    const float* W1  = (const float*)d_in[2];
    const float* b1  = (const float*)d_in[3];
    const float* g1  = (const float*)d_in[4];
    const float* bt1 = (const float*)d_in[5];
    const float* m1  = (const float*)d_in[6];
    const float* v1  = (const float*)d_in[7];
    const float* W2  = (const float*)d_in[8];
    const float* b2  = (const float*)d_in[9];
    const float* W3  = (const float*)d_in[10];
    const float* b3  = (const float*)d_in[11];
    const float* g2  = (const float*)d_in[12];
    const float* bt2 = (const float*)d_in[13];
    const float* m2  = (const float*)d_in[14];
    const float* v2  = (const float*)d_in[15];
    const float* W4  = (const float*)d_in[16];
    const float* b4  = (const float*)d_in[17];
    const float* Wc  = (const float*)d_in[18];
    const float* bc  = (const float*)d_in[19];
    float* out = (float*)d_out;

    unsigned short* B1 = (unsigned short*)d_ws;       // 40000*64*2  = 5.12 MB
    unsigned short* A2 = B1 + (size_t)NPTS * 64;      // 40000*128*2 = 10.24 MB
    float* Z = (float*)(A2 + (size_t)NPTS * 128);     // 40000*32*4  = 5.12 MB

    k1_b1<<<NPTS / 4, 256, 0, stream>>>(pos, nbr, W1, b1, B1);
    k2_conv1_mfma<<<NPTS / PTS2, 256, 0, stream>>>(pos, nbr, B1, W1, g1, bt1, m1, v1,
                                                   W2, b2, W3, b3, A2);
    k4_conv2_mfma<<<NPTS / PTS4, 256, 0, stream>>>(pos, nbr, A2, W3, g2, bt2, m2, v2,
                                                   W4, b4, Wc, Z);
    k5_softmax<<<(NPTS + 255) / 256, 256, 0, stream>>>(Z, bc, out);
}